// Round 1
// baseline (248.076 us; speedup 1.0000x reference)
//
#include <hip/hip_runtime.h>

// ---------------------------------------------------------------------------
// Head: out = softmax(mask((x@Wq)(x@Wk)^T * C^-0.5)) @ (x@Wv)
// B=4 T=4096 C=2048 H=128, fp32 in/out. bf16 MFMA pipeline.
//
// ws layout (bytes):
//   [0)        WT  bf16 [3][128][2048]   (W^T, Wq pre-scaled by C^-0.5)
//   [1572864)  Q   bf16 [16384][128]
//   [5767168)  K   bf16 [16384][128]
//   [9961472)  VT  bf16 [4][128][4096]   (V transposed per batch)
// total 14,155,776 B
// ---------------------------------------------------------------------------

typedef __attribute__((ext_vector_type(8))) short s8v;   // 8 x bf16 (4 VGPR)
typedef __attribute__((ext_vector_type(4))) float f4v;   // MFMA acc frag

__device__ __forceinline__ unsigned short f2bf(float f) {
  unsigned int b = __float_as_uint(f);
  b += 0x7FFFu + ((b >> 16) & 1u);          // round-to-nearest-even
  return (unsigned short)(b >> 16);
}

#define SCALE_QK 0.02209708691207961f       // 2048^-0.5

// ---- prep: WT[m][h][c] = Wm[c][h] (bf16); m=0 (q) pre-scaled --------------
__global__ void prep_wt(const float* __restrict__ Wq, const float* __restrict__ Wk,
                        const float* __restrict__ Wv, unsigned short* __restrict__ WT) {
  int e = blockIdx.x * 256 + threadIdx.x;   // < 3*262144
  int m = e >> 18;
  int r = e & 262143;                       // r = c*128 + h
  int c = r >> 7, h = r & 127;
  const float* W = (m == 0) ? Wq : (m == 1) ? Wk : Wv;
  float v = W[r];
  if (m == 0) v *= SCALE_QK;
  WT[m * 262144 + h * 2048 + c] = f2bf(v);
}

// ---- projection: block = 64 rows x 384 cols (q|k|v), 4 waves --------------
// wave w covers all 64 rows x cols [96w, 96w+96). K-loop BK=32, LDS dbuf,
// pad-40 rows (2-way bank conflicts only). V written transposed via LDS scr.
__global__ __launch_bounds__(256, 2) void proj_kernel(
    const float* __restrict__ x, const unsigned short* __restrict__ WT,
    unsigned short* __restrict__ Qo, unsigned short* __restrict__ Ko,
    unsigned short* __restrict__ VTo)
{
  __shared__ unsigned short Atile[2][64 * 40];    // 64 rows x 32 bf16, pad 40
  __shared__ unsigned short Btile[2][384 * 40];   // 384 cols x 32 bf16, pad 40
  __shared__ unsigned short scr[128 * 72];        // v transpose: [h][64 t], pad 72

  const int tid = threadIdx.x;
  const int wc  = tid >> 6;                 // wave id = column group
  const int lane = tid & 63;
  const int l15 = lane & 15;
  const int g   = lane >> 4;
  const int rowbase = blockIdx.x * 64;

  f4v acc[24];
  #pragma unroll
  for (int n = 0; n < 24; ++n) acc[n] = (f4v){0.f, 0.f, 0.f, 0.f};

  // staging assignment: thread -> 8 consecutive elements (16B bf16 / 32B f32)
  const int arow = tid >> 2, ach = tid & 3;
  const float* xsrc = x + (size_t)(rowbase + arow) * 2048 + ach * 8;
  const unsigned short* bsrc = WT + (size_t)arow * 2048 + ach * 8;

  // prefetch k-tile 0 into registers
  f4v xa = *(const f4v*)(xsrc);
  f4v xb = *(const f4v*)(xsrc + 4);
  s8v bw[6];
  #pragma unroll
  for (int p = 0; p < 6; ++p) bw[p] = *(const s8v*)(bsrc + (size_t)p * 131072);

  for (int it = 0; it < 64; ++it) {
    const int buf = it & 1;
    // ---- stage current tile (regs -> LDS) ----
    s8v aw;
    #pragma unroll
    for (int i = 0; i < 4; ++i) aw[i] = (short)f2bf(xa[i]);
    #pragma unroll
    for (int i = 0; i < 4; ++i) aw[i + 4] = (short)f2bf(xb[i]);
    *(s8v*)(&Atile[buf][arow * 40 + ach * 8]) = aw;
    #pragma unroll
    for (int p = 0; p < 6; ++p)
      *(s8v*)(&Btile[buf][(arow + p * 64) * 40 + ach * 8]) = bw[p];
    __syncthreads();
    // ---- prefetch next tile (overlaps compute below) ----
    if (it < 63) {
      const int k1 = (it + 1) * 32;
      xa = *(const f4v*)(xsrc + k1);
      xb = *(const f4v*)(xsrc + k1 + 4);
      #pragma unroll
      for (int p = 0; p < 6; ++p)
        bw[p] = *(const s8v*)(bsrc + k1 + (size_t)p * 131072);
    }
    // ---- fragments + MFMA ----
    s8v af[4], bfr[6];
    #pragma unroll
    for (int mi = 0; mi < 4; ++mi)
      af[mi] = *(const s8v*)(&Atile[buf][(mi * 16 + l15) * 40 + g * 8]);
    #pragma unroll
    for (int nl = 0; nl < 6; ++nl)
      bfr[nl] = *(const s8v*)(&Btile[buf][((6 * wc + nl) * 16 + l15) * 40 + g * 8]);
    #pragma unroll
    for (int mi = 0; mi < 4; ++mi)
      #pragma unroll
      for (int nl = 0; nl < 6; ++nl)
        acc[mi * 6 + nl] = __builtin_amdgcn_mfma_f32_16x16x32_bf16(
            af[mi], bfr[nl], acc[mi * 6 + nl], 0, 0, 0);
    // single barrier/iter is safe: next iter writes the other buffer; the
    // iter-(it+1) barrier separates iter-it reads from iter-(it+2) writes.
  }

  // ---- epilogue: q,k direct; v -> LDS transpose -> VT ----
  #pragma unroll
  for (int mi = 0; mi < 4; ++mi) {
    #pragma unroll
    for (int nl = 0; nl < 6; ++nl) {
      const int colg = 96 * wc + 16 * nl + l15;   // 0..383
      const int m = colg >> 7;                    // 0=q 1=k 2=v
      const int h = colg & 127;
      const f4v a = acc[mi * 6 + nl];
      if (m < 2) {
        unsigned short* dst = (m == 0) ? Qo : Ko;
        #pragma unroll
        for (int r = 0; r < 4; ++r) {
          const int t = rowbase + mi * 16 + 4 * g + r;
          dst[(size_t)t * 128 + h] = f2bf(a[r]);
        }
      } else {
        #pragma unroll
        for (int r = 0; r < 4; ++r) {
          const int tl = mi * 16 + 4 * g + r;     // 0..63
          scr[h * 72 + tl] = f2bf(a[r]);
        }
      }
    }
  }
  __syncthreads();
  {
    const int b   = rowbase >> 12;
    const int tg0 = rowbase & 4095;
    const int h    = tid >> 1;
    const int toff = (tid & 1) * 32;
    unsigned short* dst = VTo + (size_t)(b * 128 + h) * 4096 + tg0 + toff;
    #pragma unroll
    for (int q2 = 0; q2 < 4; ++q2) {
      s8v vv = *(const s8v*)(&scr[h * 72 + toff + q2 * 8]);
      *(s8v*)(dst + q2 * 8) = vv;
    }
  }
}

// ---- attention: 1 wave per 16-row q strip, KV tile 32, flash softmax ------
// All MFMA operand loads are contiguous 16B/lane from global (L2-resident).
// P goes through a 1.25KB per-block LDS roundtrip (D-layout -> A-layout).
__global__ __launch_bounds__(64, 2) void attn_kernel(
    const unsigned short* __restrict__ Q, const unsigned short* __restrict__ K,
    const unsigned short* __restrict__ VT, float* __restrict__ out)
{
  __shared__ unsigned short plds[16 * 40];
  const int lane = threadIdx.x;
  const int l15 = lane & 15, g = lane >> 4;

  const int b  = blockIdx.x & 3;
  const int jj = blockIdx.x >> 2;           // 0..255
  const int qb = (255 - jj) * 16;           // descending work (LPT balance)

  const unsigned short* Qb = Q  + (size_t)b * 4096 * 128;
  const unsigned short* Kb = K  + (size_t)b * 4096 * 128;
  const unsigned short* Vb = VT + (size_t)b * 128 * 4096;

  s8v qf[4];
  #pragma unroll
  for (int kk = 0; kk < 4; ++kk)
    qf[kk] = *(const s8v*)(Qb + (size_t)(qb + l15) * 128 + kk * 32 + g * 8);

  f4v o[8];
  #pragma unroll
  for (int n = 0; n < 8; ++n) o[n] = (f4v){0.f, 0.f, 0.f, 0.f};
  float mrun[4], lrun[4];
  #pragma unroll
  for (int r = 0; r < 4; ++r) { mrun[r] = -1e30f; lrun[r] = 0.f; }

  const int ntiles = (qb + 47) >> 5;
  for (int t = 0; t < ntiles; ++t) {
    const int kvb = t * 32;
    s8v kf0[4], kf1[4];
    #pragma unroll
    for (int kk = 0; kk < 4; ++kk) {
      kf0[kk] = *(const s8v*)(Kb + (size_t)(kvb + l15) * 128 + kk * 32 + g * 8);
      kf1[kk] = *(const s8v*)(Kb + (size_t)(kvb + 16 + l15) * 128 + kk * 32 + g * 8);
    }
    s8v vf[8];                               // issued early: in flight during S
    #pragma unroll
    for (int n = 0; n < 8; ++n)
      vf[n] = *(const s8v*)(Vb + (size_t)(16 * n + l15) * 4096 + kvb + g * 8);

    f4v s0 = (f4v){0.f, 0.f, 0.f, 0.f}, s1 = (f4v){0.f, 0.f, 0.f, 0.f};
    #pragma unroll
    for (int kk = 0; kk < 4; ++kk) {
      s0 = __builtin_amdgcn_mfma_f32_16x16x32_bf16(qf[kk], kf0[kk], s0, 0, 0, 0);
      s1 = __builtin_amdgcn_mfma_f32_16x16x32_bf16(qf[kk], kf1[kk], s1, 0, 0, 0);
    }
    if (t == ntiles - 1) {                   // only the diagonal tile masks
      #pragma unroll
      for (int r = 0; r < 4; ++r) {
        const int qrow = qb + 4 * g + r;
        if (kvb + l15 > qrow)      s0[r] = -1e30f;
        if (kvb + 16 + l15 > qrow) s1[r] = -1e30f;
      }
    }
    // wave-parallel online softmax (rows live in 16-lane column groups)
    float corr[4];
    f4v p0, p1;
    #pragma unroll
    for (int r = 0; r < 4; ++r) {
      float v = fmaxf(s0[r], s1[r]);
      v = fmaxf(v, __shfl_xor(v, 1));
      v = fmaxf(v, __shfl_xor(v, 2));
      v = fmaxf(v, __shfl_xor(v, 4));
      v = fmaxf(v, __shfl_xor(v, 8));
      const float mnew = fmaxf(mrun[r], v);
      corr[r] = __expf(mrun[r] - mnew);
      mrun[r] = mnew;
      p0[r] = __expf(s0[r] - mnew);
      p1[r] = __expf(s1[r] - mnew);
      float s = p0[r] + p1[r];
      s += __shfl_xor(s, 1);
      s += __shfl_xor(s, 2);
      s += __shfl_xor(s, 4);
      s += __shfl_xor(s, 8);
      lrun[r] = lrun[r] * corr[r] + s;
    }
    #pragma unroll
    for (int n = 0; n < 8; ++n)
      #pragma unroll
      for (int r = 0; r < 4; ++r) o[n][r] *= corr[r];
    // P: D-layout -> LDS -> A-layout (same-wave DS ops are in-order)
    #pragma unroll
    for (int r = 0; r < 4; ++r) {
      plds[(4 * g + r) * 40 + l15]      = f2bf(p0[r]);
      plds[(4 * g + r) * 40 + 16 + l15] = f2bf(p1[r]);
    }
    s8v pf = *(const s8v*)(&plds[l15 * 40 + g * 8]);
    #pragma unroll
    for (int n = 0; n < 8; ++n)
      o[n] = __builtin_amdgcn_mfma_f32_16x16x32_bf16(pf, vf[n], o[n], 0, 0, 0);
  }

  #pragma unroll
  for (int r = 0; r < 4; ++r) {
    const float inv = 1.0f / lrun[r];
    const size_t row = (size_t)(b * 4096 + qb + 4 * g + r) * 128;
    #pragma unroll
    for (int n = 0; n < 8; ++n)
      out[row + 16 * n + l15] = o[n][r] * inv;
  }
}

extern "C" void kernel_launch(void* const* d_in, const int* in_sizes, int n_in,
                              void* d_out, int out_size, void* d_ws, size_t ws_size,
                              hipStream_t stream) {
  const float* x  = (const float*)d_in[0];
  const float* Wq = (const float*)d_in[1];
  const float* Wk = (const float*)d_in[2];
  const float* Wv = (const float*)d_in[3];

  unsigned short* WT = (unsigned short*)d_ws;
  unsigned short* Q  = (unsigned short*)((char*)d_ws + 1572864);
  unsigned short* K  = (unsigned short*)((char*)d_ws + 5767168);
  unsigned short* VT = (unsigned short*)((char*)d_ws + 9961472);
  float* out = (float*)d_out;

  prep_wt<<<3072, 256, 0, stream>>>(Wq, Wk, Wv, WT);
  proj_kernel<<<256, 256, 0, stream>>>(x, WT, Q, K, VT);
  attn_kernel<<<1024, 64, 0, stream>>>(Q, K, VT, out);
}

// Round 2
// 232.042 us; speedup vs baseline: 1.0691x; 1.0691x over previous
//
#include <hip/hip_runtime.h>

// ---------------------------------------------------------------------------
// Head: out = softmax(mask((x@Wq)(x@Wk)^T * C^-0.5)) @ (x@Wv)
// B=4 T=4096 C=2048 H=128, fp32 in/out. bf16 MFMA pipeline.
//
// ws layout (bytes):
//   [0)        WT  bf16 [3][128][2048]   (W^T, Wq pre-scaled by C^-0.5)
//   [1572864)  Q   bf16 [16384][128]
//   [5767168)  K   bf16 [16384][128]
//   [9961472)  VT  bf16 [4][128][4096]   (V transposed per batch)
// total 14,155,776 B
// ---------------------------------------------------------------------------

typedef __attribute__((ext_vector_type(8))) short s8v;   // 8 x bf16 (4 VGPR)
typedef __attribute__((ext_vector_type(4))) float f4v;   // MFMA acc frag

__device__ __forceinline__ unsigned short f2bf(float f) {
  unsigned int b = __float_as_uint(f);
  b += 0x7FFFu + ((b >> 16) & 1u);          // round-to-nearest-even
  return (unsigned short)(b >> 16);
}

#define SCALE_QK 0.02209708691207961f       // 2048^-0.5

// ---- prep: WT[m][h][c] = Wm[c][h] (bf16); m=0 (q) pre-scaled --------------
__global__ void prep_wt(const float* __restrict__ Wq, const float* __restrict__ Wk,
                        const float* __restrict__ Wv, unsigned short* __restrict__ WT) {
  int e = blockIdx.x * 256 + threadIdx.x;   // < 3*262144
  int m = e >> 18;
  int r = e & 262143;                       // r = c*128 + h
  int c = r >> 7, h = r & 127;
  const float* W = (m == 0) ? Wq : (m == 1) ? Wk : Wv;
  float v = W[r];
  if (m == 0) v *= SCALE_QK;
  WT[m * 262144 + h * 2048 + c] = f2bf(v);
}

// ---- projection: block = 64 rows x 384 cols (q|k|v), 4 waves --------------
__global__ __launch_bounds__(256, 2) void proj_kernel(
    const float* __restrict__ x, const unsigned short* __restrict__ WT,
    unsigned short* __restrict__ Qo, unsigned short* __restrict__ Ko,
    unsigned short* __restrict__ VTo)
{
  __shared__ unsigned short Atile[2][64 * 40];    // 64 rows x 32 bf16, pad 40
  __shared__ unsigned short Btile[2][384 * 40];   // 384 cols x 32 bf16, pad 40
  __shared__ unsigned short scr[128 * 72];        // v transpose: [h][64 t], pad 72

  const int tid = threadIdx.x;
  const int wc  = tid >> 6;                 // wave id = column group
  const int lane = tid & 63;
  const int l15 = lane & 15;
  const int g   = lane >> 4;
  const int rowbase = blockIdx.x * 64;

  f4v acc[24];
  #pragma unroll
  for (int n = 0; n < 24; ++n) acc[n] = (f4v){0.f, 0.f, 0.f, 0.f};

  const int arow = tid >> 2, ach = tid & 3;
  const float* xsrc = x + (size_t)(rowbase + arow) * 2048 + ach * 8;
  const unsigned short* bsrc = WT + (size_t)arow * 2048 + ach * 8;

  f4v xa = *(const f4v*)(xsrc);
  f4v xb = *(const f4v*)(xsrc + 4);
  s8v bw[6];
  #pragma unroll
  for (int p = 0; p < 6; ++p) bw[p] = *(const s8v*)(bsrc + (size_t)p * 131072);

  for (int it = 0; it < 64; ++it) {
    const int buf = it & 1;
    s8v aw;
    #pragma unroll
    for (int i = 0; i < 4; ++i) aw[i] = (short)f2bf(xa[i]);
    #pragma unroll
    for (int i = 0; i < 4; ++i) aw[i + 4] = (short)f2bf(xb[i]);
    *(s8v*)(&Atile[buf][arow * 40 + ach * 8]) = aw;
    #pragma unroll
    for (int p = 0; p < 6; ++p)
      *(s8v*)(&Btile[buf][(arow + p * 64) * 40 + ach * 8]) = bw[p];
    __syncthreads();
    if (it < 63) {
      const int k1 = (it + 1) * 32;
      xa = *(const f4v*)(xsrc + k1);
      xb = *(const f4v*)(xsrc + k1 + 4);
      #pragma unroll
      for (int p = 0; p < 6; ++p)
        bw[p] = *(const s8v*)(bsrc + k1 + (size_t)p * 131072);
    }
    s8v af[4], bfr[6];
    #pragma unroll
    for (int mi = 0; mi < 4; ++mi)
      af[mi] = *(const s8v*)(&Atile[buf][(mi * 16 + l15) * 40 + g * 8]);
    #pragma unroll
    for (int nl = 0; nl < 6; ++nl)
      bfr[nl] = *(const s8v*)(&Btile[buf][((6 * wc + nl) * 16 + l15) * 40 + g * 8]);
    #pragma unroll
    for (int mi = 0; mi < 4; ++mi)
      #pragma unroll
      for (int nl = 0; nl < 6; ++nl)
        acc[mi * 6 + nl] = __builtin_amdgcn_mfma_f32_16x16x32_bf16(
            af[mi], bfr[nl], acc[mi * 6 + nl], 0, 0, 0);
  }

  #pragma unroll
  for (int mi = 0; mi < 4; ++mi) {
    #pragma unroll
    for (int nl = 0; nl < 6; ++nl) {
      const int colg = 96 * wc + 16 * nl + l15;   // 0..383
      const int m = colg >> 7;                    // 0=q 1=k 2=v
      const int h = colg & 127;
      const f4v a = acc[mi * 6 + nl];
      if (m < 2) {
        unsigned short* dst = (m == 0) ? Qo : Ko;
        #pragma unroll
        for (int r = 0; r < 4; ++r) {
          const int t = rowbase + mi * 16 + 4 * g + r;
          dst[(size_t)t * 128 + h] = f2bf(a[r]);
        }
      } else {
        #pragma unroll
        for (int r = 0; r < 4; ++r) {
          const int tl = mi * 16 + 4 * g + r;     // 0..63
          scr[h * 72 + tl] = f2bf(a[r]);
        }
      }
    }
  }
  __syncthreads();
  {
    const int b   = rowbase >> 12;
    const int tg0 = rowbase & 4095;
    const int h    = tid >> 1;
    const int toff = (tid & 1) * 32;
    unsigned short* dst = VTo + (size_t)(b * 128 + h) * 4096 + tg0 + toff;
    #pragma unroll
    for (int q2 = 0; q2 < 4; ++q2) {
      s8v vv = *(const s8v*)(&scr[h * 72 + toff + q2 * 8]);
      *(s8v*)(dst + q2 * 8) = vv;
    }
  }
}

// ---- attention: 4 waves per 16-row q strip; each wave owns a contiguous ---
// quarter of the KV range (flash partials m/l/o), merged via LDS at the end.
// 1024 blocks x 256 thr -> 4096 waves -> 4 waves/SIMD (TLP latency hiding).
__global__ __launch_bounds__(256, 4) void attn_kernel(
    const unsigned short* __restrict__ Q, const unsigned short* __restrict__ K,
    const unsigned short* __restrict__ VT, float* __restrict__ out)
{
  __shared__ unsigned short plds[4][16 * 40];   // per-wave P roundtrip
  __shared__ float o_lds[4][16][132];           // per-wave unnormalized o
  __shared__ float ml[4][16][2];                // per-wave {m, l}

  const int tid  = threadIdx.x;
  const int w    = tid >> 6;                    // wave id 0..3
  const int lane = tid & 63;
  const int l15 = lane & 15, g = lane >> 4;

  const int b  = blockIdx.x & 3;
  const int jj = blockIdx.x >> 2;               // 0..255
  const int qb = (255 - jj) * 16;               // descending work (LPT balance)

  const unsigned short* Qb = Q  + (size_t)b * 4096 * 128;
  const unsigned short* Kb = K  + (size_t)b * 4096 * 128;
  const unsigned short* Vb = VT + (size_t)b * 128 * 4096;

  // KV range for this wave: units of 16 cols, contiguous quarter
  const int N16 = (qb >> 4) + 1;
  const int upw = (N16 + 3) >> 2;
  const int u0  = min(w * upw, N16);
  const int u1  = min(u0 + upw, N16);
  const int c0  = u0 * 16;
  const int c1  = u1 * 16;

  s8v qf[4];
  #pragma unroll
  for (int kk = 0; kk < 4; ++kk)
    qf[kk] = *(const s8v*)(Qb + (size_t)(qb + l15) * 128 + kk * 32 + g * 8);

  f4v o[8];
  #pragma unroll
  for (int n = 0; n < 8; ++n) o[n] = (f4v){0.f, 0.f, 0.f, 0.f};
  float mrun[4], lrun[4];
  #pragma unroll
  for (int r = 0; r < 4; ++r) { mrun[r] = -1e30f; lrun[r] = 0.f; }

  for (int kvb = c0; kvb < c1; kvb += 32) {
    // --- K fragments, QK^T ---
    s8v kf0[4], kf1[4];
    #pragma unroll
    for (int kk = 0; kk < 4; ++kk) {
      kf0[kk] = *(const s8v*)(Kb + (size_t)(kvb + l15) * 128 + kk * 32 + g * 8);
      kf1[kk] = *(const s8v*)(Kb + (size_t)(kvb + 16 + l15) * 128 + kk * 32 + g * 8);
    }
    f4v s0 = (f4v){0.f, 0.f, 0.f, 0.f}, s1 = (f4v){0.f, 0.f, 0.f, 0.f};
    #pragma unroll
    for (int kk = 0; kk < 4; ++kk) {
      s0 = __builtin_amdgcn_mfma_f32_16x16x32_bf16(qf[kk], kf0[kk], s0, 0, 0, 0);
      s1 = __builtin_amdgcn_mfma_f32_16x16x32_bf16(qf[kk], kf1[kk], s1, 0, 0, 0);
    }
    // --- V loads issued now: latency hides under softmax VALU + TLP ---
    s8v vf[8];
    #pragma unroll
    for (int n = 0; n < 8; ++n)
      vf[n] = *(const s8v*)(Vb + (size_t)(16 * n + l15) * 4096 + kvb + g * 8);

    // --- masking (causal + own-range tail), only when tile needs it ---
    if (kvb + 31 > qb || kvb + 32 > c1) {
      #pragma unroll
      for (int r = 0; r < 4; ++r) {
        const int qrow = qb + 4 * g + r;
        const int ca = kvb + l15, cb = kvb + 16 + l15;
        if (ca > qrow || ca >= c1) s0[r] = -1e30f;
        if (cb > qrow || cb >= c1) s1[r] = -1e30f;
      }
    }
    // --- online softmax: per-tile max reduce; l kept as per-lane partials ---
    float pmax[4];
    #pragma unroll
    for (int r = 0; r < 4; ++r) {
      float v = fmaxf(s0[r], s1[r]);
      v = fmaxf(v, __shfl_xor(v, 1));
      v = fmaxf(v, __shfl_xor(v, 2));
      v = fmaxf(v, __shfl_xor(v, 4));
      v = fmaxf(v, __shfl_xor(v, 8));
      pmax[r] = v;
    }
    bool grow = false;
    #pragma unroll
    for (int r = 0; r < 4; ++r) grow |= (pmax[r] > mrun[r] + 4.0f);
    if (__any(grow)) {                         // defer-max: rescale only on growth
      float corr[4];
      #pragma unroll
      for (int r = 0; r < 4; ++r) {
        const float mnew = fmaxf(mrun[r], pmax[r]);
        corr[r] = __expf(mrun[r] - mnew);
        mrun[r] = mnew;
        lrun[r] *= corr[r];
      }
      #pragma unroll
      for (int n = 0; n < 8; ++n)
        #pragma unroll
        for (int r = 0; r < 4; ++r) o[n][r] *= corr[r];
    }
    f4v p0, p1;
    #pragma unroll
    for (int r = 0; r < 4; ++r) {
      p0[r] = __expf(s0[r] - mrun[r]);
      p1[r] = __expf(s1[r] - mrun[r]);
      lrun[r] += p0[r] + p1[r];                // per-lane partial sum
    }
    // --- P: D-layout -> LDS -> A-layout (per-wave buffer, same-wave order) ---
    #pragma unroll
    for (int r = 0; r < 4; ++r) {
      plds[w][(4 * g + r) * 40 + l15]      = f2bf(p0[r]);
      plds[w][(4 * g + r) * 40 + 16 + l15] = f2bf(p1[r]);
    }
    s8v pf = *(const s8v*)(&plds[w][l15 * 40 + g * 8]);
    #pragma unroll
    for (int n = 0; n < 8; ++n)
      o[n] = __builtin_amdgcn_mfma_f32_16x16x32_bf16(pf, vf[n], o[n], 0, 0, 0);
  }

  // --- per-wave finish: reduce l across the 16-lane group, dump partials ---
  #pragma unroll
  for (int r = 0; r < 4; ++r) {
    float s = lrun[r];
    s += __shfl_xor(s, 1);
    s += __shfl_xor(s, 2);
    s += __shfl_xor(s, 4);
    s += __shfl_xor(s, 8);
    if (l15 == 0) {
      ml[w][4 * g + r][0] = mrun[r];
      ml[w][4 * g + r][1] = s;
    }
  }
  #pragma unroll
  for (int n = 0; n < 8; ++n)
    #pragma unroll
    for (int r = 0; r < 4; ++r)
      o_lds[w][4 * g + r][16 * n + l15] = o[n][r];
  __syncthreads();

  // --- combine 4 partials; thread t: row = t>>4, 8 h's ---
  {
    const int row = tid >> 4;
    const int hb  = (tid & 15) * 8;
    float M = -1e30f;
    #pragma unroll
    for (int p = 0; p < 4; ++p) M = fmaxf(M, ml[p][row][0]);
    float lt = 0.f;
    float oc[8];
    #pragma unroll
    for (int j = 0; j < 8; ++j) oc[j] = 0.f;
    #pragma unroll
    for (int p = 0; p < 4; ++p) {
      const float wgt = __expf(ml[p][row][0] - M);
      lt += wgt * ml[p][row][1];
      #pragma unroll
      for (int j = 0; j < 8; ++j) oc[j] += wgt * o_lds[p][row][hb + j];
    }
    const float inv = 1.0f / lt;
    float* dst = out + (size_t)(b * 4096 + qb + row) * 128 + hb;
    #pragma unroll
    for (int j = 0; j < 8; ++j) dst[j] = oc[j] * inv;
  }
}

extern "C" void kernel_launch(void* const* d_in, const int* in_sizes, int n_in,
                              void* d_out, int out_size, void* d_ws, size_t ws_size,
                              hipStream_t stream) {
  const float* x  = (const float*)d_in[0];
  const float* Wq = (const float*)d_in[1];
  const float* Wk = (const float*)d_in[2];
  const float* Wv = (const float*)d_in[3];

  unsigned short* WT = (unsigned short*)d_ws;
  unsigned short* Q  = (unsigned short*)((char*)d_ws + 1572864);
  unsigned short* K  = (unsigned short*)((char*)d_ws + 5767168);
  unsigned short* VT = (unsigned short*)((char*)d_ws + 9961472);
  float* out = (float*)d_out;

  prep_wt<<<3072, 256, 0, stream>>>(Wq, Wk, Wv, WT);
  proj_kernel<<<256, 256, 0, stream>>>(x, WT, Q, K, VT);
  attn_kernel<<<1024, 256, 0, stream>>>(Q, K, VT, out);
}

// Round 3
// 194.268 us; speedup vs baseline: 1.2770x; 1.1944x over previous
//
#include <hip/hip_runtime.h>

// ---------------------------------------------------------------------------
// Head: out = softmax(mask((x@Wq)(x@Wk)^T * C^-0.5)) @ (x@Wv)
// B=4 T=4096 C=2048 H=128, fp32 in/out. bf16 MFMA pipeline.
//
// ws layout (bytes):
//   [0)        WT  bf16 [3][128][2048]   (W^T, Wq pre-scaled by C^-0.5)
//   [1572864)  Q   bf16 [16384][128]
//   [5767168)  K   bf16 [16384][128]
//   [9961472)  VT  bf16 [4][128][4096]   (V transposed per batch)
// total 14,155,776 B
// ---------------------------------------------------------------------------

typedef __attribute__((ext_vector_type(8))) short s8v;   // 8 x bf16 (4 VGPR)
typedef __attribute__((ext_vector_type(4))) float f4v;   // MFMA acc frag

__device__ __forceinline__ unsigned short f2bf(float f) {
  unsigned int b = __float_as_uint(f);
  b += 0x7FFFu + ((b >> 16) & 1u);          // round-to-nearest-even
  return (unsigned short)(b >> 16);
}

#define SCALE_QK 0.02209708691207961f       // 2048^-0.5

// ---- prep: WT[m][h][c] = Wm[c][h] (bf16); m=0 (q) pre-scaled --------------
__global__ void prep_wt(const float* __restrict__ Wq, const float* __restrict__ Wk,
                        const float* __restrict__ Wv, unsigned short* __restrict__ WT) {
  int e = blockIdx.x * 256 + threadIdx.x;   // < 3*262144
  int m = e >> 18;
  int r = e & 262143;                       // r = c*128 + h
  int c = r >> 7, h = r & 127;
  const float* W = (m == 0) ? Wq : (m == 1) ? Wk : Wv;
  float v = W[r];
  if (m == 0) v *= SCALE_QK;
  WT[m * 262144 + h * 2048 + c] = f2bf(v);
}

// ---- projection: block = 64 rows x 384 cols (q|k|v), 4 waves --------------
__global__ __launch_bounds__(256, 2) void proj_kernel(
    const float* __restrict__ x, const unsigned short* __restrict__ WT,
    unsigned short* __restrict__ Qo, unsigned short* __restrict__ Ko,
    unsigned short* __restrict__ VTo)
{
  __shared__ unsigned short Atile[2][64 * 40];    // 64 rows x 32 bf16, pad 40
  __shared__ unsigned short Btile[2][384 * 40];   // 384 cols x 32 bf16, pad 40
  __shared__ unsigned short scr[128 * 72];        // v transpose: [h][64 t], pad 72

  const int tid = threadIdx.x;
  const int wc  = tid >> 6;                 // wave id = column group
  const int lane = tid & 63;
  const int l15 = lane & 15;
  const int g   = lane >> 4;
  const int rowbase = blockIdx.x * 64;

  f4v acc[24];
  #pragma unroll
  for (int n = 0; n < 24; ++n) acc[n] = (f4v){0.f, 0.f, 0.f, 0.f};

  const int arow = tid >> 2, ach = tid & 3;
  const float* xsrc = x + (size_t)(rowbase + arow) * 2048 + ach * 8;
  const unsigned short* bsrc = WT + (size_t)arow * 2048 + ach * 8;

  f4v xa = *(const f4v*)(xsrc);
  f4v xb = *(const f4v*)(xsrc + 4);
  s8v bw[6];
  #pragma unroll
  for (int p = 0; p < 6; ++p) bw[p] = *(const s8v*)(bsrc + (size_t)p * 131072);

  for (int it = 0; it < 64; ++it) {
    const int buf = it & 1;
    s8v aw;
    #pragma unroll
    for (int i = 0; i < 4; ++i) aw[i] = (short)f2bf(xa[i]);
    #pragma unroll
    for (int i = 0; i < 4; ++i) aw[i + 4] = (short)f2bf(xb[i]);
    *(s8v*)(&Atile[buf][arow * 40 + ach * 8]) = aw;
    #pragma unroll
    for (int p = 0; p < 6; ++p)
      *(s8v*)(&Btile[buf][(arow + p * 64) * 40 + ach * 8]) = bw[p];
    __syncthreads();
    if (it < 63) {
      const int k1 = (it + 1) * 32;
      xa = *(const f4v*)(xsrc + k1);
      xb = *(const f4v*)(xsrc + k1 + 4);
      #pragma unroll
      for (int p = 0; p < 6; ++p)
        bw[p] = *(const s8v*)(bsrc + k1 + (size_t)p * 131072);
    }
    s8v af[4], bfr[6];
    #pragma unroll
    for (int mi = 0; mi < 4; ++mi)
      af[mi] = *(const s8v*)(&Atile[buf][(mi * 16 + l15) * 40 + g * 8]);
    #pragma unroll
    for (int nl = 0; nl < 6; ++nl)
      bfr[nl] = *(const s8v*)(&Btile[buf][((6 * wc + nl) * 16 + l15) * 40 + g * 8]);
    #pragma unroll
    for (int mi = 0; mi < 4; ++mi)
      #pragma unroll
      for (int nl = 0; nl < 6; ++nl)
        acc[mi * 6 + nl] = __builtin_amdgcn_mfma_f32_16x16x32_bf16(
            af[mi], bfr[nl], acc[mi * 6 + nl], 0, 0, 0);
  }

  #pragma unroll
  for (int mi = 0; mi < 4; ++mi) {
    #pragma unroll
    for (int nl = 0; nl < 6; ++nl) {
      const int colg = 96 * wc + 16 * nl + l15;   // 0..383
      const int m = colg >> 7;                    // 0=q 1=k 2=v
      const int h = colg & 127;
      const f4v a = acc[mi * 6 + nl];
      if (m < 2) {
        unsigned short* dst = (m == 0) ? Qo : Ko;
        #pragma unroll
        for (int r = 0; r < 4; ++r) {
          const int t = rowbase + mi * 16 + 4 * g + r;
          dst[(size_t)t * 128 + h] = f2bf(a[r]);
        }
      } else {
        #pragma unroll
        for (int r = 0; r < 4; ++r) {
          const int tl = mi * 16 + 4 * g + r;     // 0..63
          scr[h * 72 + tl] = f2bf(a[r]);
        }
      }
    }
  }
  __syncthreads();
  {
    const int b   = rowbase >> 12;
    const int tg0 = rowbase & 4095;
    const int h    = tid >> 1;
    const int toff = (tid & 1) * 32;
    unsigned short* dst = VTo + (size_t)(b * 128 + h) * 4096 + tg0 + toff;
    #pragma unroll
    for (int q2 = 0; q2 < 4; ++q2) {
      s8v vv = *(const s8v*)(&scr[h * 72 + toff + q2 * 8]);
      *(s8v*)(dst + q2 * 8) = vv;
    }
  }
}

// ---- attention ------------------------------------------------------------
// Block = 4 waves, TWO paired q-strips {16*jj, 4080-16*jj}; each strip's KV
// range split across 2 waves (flash partials, merged via LDS). Every block
// has identical work (4112 KV cols) -> no co-residency imbalance.
// KVBLK=64: 32 MFMA per iteration amortize the softmax/DS chain.
__global__ __launch_bounds__(256, 2) void attn_kernel(
    const unsigned short* __restrict__ Q, const unsigned short* __restrict__ K,
    const unsigned short* __restrict__ VT, float* __restrict__ out)
{
  __shared__ __align__(16) unsigned short plds[4][16 * 72]; // per-wave P bounce
  __shared__ __align__(16) float o_lds[4][16][132];         // per-wave o partial
  __shared__ float ml[4][16][2];                            // per-wave {m, l}

  const int tid  = threadIdx.x;
  const int w    = tid >> 6;                 // wave 0..3
  const int lane = tid & 63;
  const int l15 = lane & 15, g = lane >> 4;

  const int b  = blockIdx.x & 3;
  const int jj = blockIdx.x >> 2;            // 0..127
  const int strip = w >> 1, half = w & 1;
  const int qb = strip ? (4080 - jj * 16) : (jj * 16);

  const unsigned short* Qb = Q  + (size_t)b * 4096 * 128;
  const unsigned short* Kb = K  + (size_t)b * 4096 * 128;
  const unsigned short* Vb = VT + (size_t)b * 128 * 4096;

  // this wave's KV half (units of 16 cols)
  const int N16 = (qb >> 4) + 1;
  const int uh  = (N16 + 1) >> 1;
  const int u0  = half * uh;
  const int u1  = min(u0 + uh, N16);
  const int c0  = u0 * 16, c1 = u1 * 16;

  s8v qf[4];
  #pragma unroll
  for (int kk = 0; kk < 4; ++kk)
    qf[kk] = *(const s8v*)(Qb + (size_t)(qb + l15) * 128 + kk * 32 + g * 8);

  f4v o[8];
  #pragma unroll
  for (int n = 0; n < 8; ++n) o[n] = (f4v){0.f, 0.f, 0.f, 0.f};
  float mrun[4], lrun[4];
  #pragma unroll
  for (int r = 0; r < 4; ++r) { mrun[r] = -1e30f; lrun[r] = 0.f; }

  for (int kvb = c0; kvb < c1; kvb += 64) {
    // --- K fragments: 4 subtiles x 4 k-chunks (row-clamped: clamped rows
    //     are always masked below, so duplicate data is harmless) ---
    s8v kf[4][4];
    #pragma unroll
    for (int t = 0; t < 4; ++t) {
      const int rt = min(kvb + 16 * t + l15, 4095);
      #pragma unroll
      for (int kk = 0; kk < 4; ++kk)
        kf[t][kk] = *(const s8v*)(Kb + (size_t)rt * 128 + kk * 32 + g * 8);
    }
    // --- V fragments for both K=32 halves (col-clamped; P=0 there) ---
    s8v vf[2][8];
    #pragma unroll
    for (int h2 = 0; h2 < 2; ++h2) {
      const int cb = min(kvb + 32 * h2 + g * 8, 4088);
      #pragma unroll
      for (int n = 0; n < 8; ++n)
        vf[h2][n] = *(const s8v*)(Vb + (size_t)(16 * n + l15) * 4096 + cb);
    }
    // --- QK^T: 16 MFMA (waits only on K loads; V stays in flight) ---
    f4v s[4];
    #pragma unroll
    for (int t = 0; t < 4; ++t) s[t] = (f4v){0.f, 0.f, 0.f, 0.f};
    __builtin_amdgcn_s_setprio(1);
    #pragma unroll
    for (int kk = 0; kk < 4; ++kk)
      #pragma unroll
      for (int t = 0; t < 4; ++t)
        s[t] = __builtin_amdgcn_mfma_f32_16x16x32_bf16(qf[kk], kf[t][kk], s[t], 0, 0, 0);
    __builtin_amdgcn_s_setprio(0);
    // --- masking (diagonal and/or range tail only) ---
    if (kvb + 63 > qb || kvb + 64 > c1) {
      #pragma unroll
      for (int t = 0; t < 4; ++t)
        #pragma unroll
        for (int r = 0; r < 4; ++r) {
          const int kv = kvb + 16 * t + l15;
          if (kv > qb + 4 * g + r || kv >= c1) s[t][r] = -1e30f;
        }
    }
    // --- online softmax: in-lane max over 4 subtiles, then 4-shuffle reduce ---
    float pmax[4];
    #pragma unroll
    for (int r = 0; r < 4; ++r) {
      float v = fmaxf(fmaxf(s[0][r], s[1][r]), fmaxf(s[2][r], s[3][r]));
      v = fmaxf(v, __shfl_xor(v, 1));
      v = fmaxf(v, __shfl_xor(v, 2));
      v = fmaxf(v, __shfl_xor(v, 4));
      v = fmaxf(v, __shfl_xor(v, 8));
      pmax[r] = v;
    }
    bool grow = false;
    #pragma unroll
    for (int r = 0; r < 4; ++r) grow |= (pmax[r] > mrun[r] + 4.0f);
    if (__any(grow)) {                       // defer-max (T13)
      #pragma unroll
      for (int r = 0; r < 4; ++r) {
        const float mnew = fmaxf(mrun[r], pmax[r]);
        const float corr = __expf(mrun[r] - mnew);
        mrun[r] = mnew;
        lrun[r] *= corr;
        #pragma unroll
        for (int n = 0; n < 8; ++n) o[n][r] *= corr;
      }
    }
    f4v p[4];
    #pragma unroll
    for (int t = 0; t < 4; ++t)
      #pragma unroll
      for (int r = 0; r < 4; ++r) {
        p[t][r] = __expf(s[t][r] - mrun[r]);
      }
    #pragma unroll
    for (int r = 0; r < 4; ++r)
      lrun[r] += (p[0][r] + p[1][r]) + (p[2][r] + p[3][r]);
    // --- P: D-layout -> LDS -> two A-fragments (stride 72 = 2-way only) ---
    #pragma unroll
    for (int t = 0; t < 4; ++t)
      #pragma unroll
      for (int r = 0; r < 4; ++r)
        plds[w][(4 * g + r) * 72 + 16 * t + l15] = f2bf(p[t][r]);
    const s8v pf0 = *(const s8v*)(&plds[w][l15 * 72 + g * 8]);
    const s8v pf1 = *(const s8v*)(&plds[w][l15 * 72 + 32 + g * 8]);
    // --- PV: 16 MFMA ---
    __builtin_amdgcn_s_setprio(1);
    #pragma unroll
    for (int n = 0; n < 8; ++n)
      o[n] = __builtin_amdgcn_mfma_f32_16x16x32_bf16(pf0, vf[0][n], o[n], 0, 0, 0);
    #pragma unroll
    for (int n = 0; n < 8; ++n)
      o[n] = __builtin_amdgcn_mfma_f32_16x16x32_bf16(pf1, vf[1][n], o[n], 0, 0, 0);
    __builtin_amdgcn_s_setprio(0);
  }

  // --- per-wave finish: reduce l across the 16-lane group, dump partials ---
  #pragma unroll
  for (int r = 0; r < 4; ++r) {
    float s = lrun[r];
    s += __shfl_xor(s, 1);
    s += __shfl_xor(s, 2);
    s += __shfl_xor(s, 4);
    s += __shfl_xor(s, 8);
    if (l15 == 0) {
      ml[w][4 * g + r][0] = mrun[r];
      ml[w][4 * g + r][1] = s;
    }
  }
  #pragma unroll
  for (int n = 0; n < 8; ++n)
    #pragma unroll
    for (int r = 0; r < 4; ++r)
      o_lds[w][4 * g + r][16 * n + l15] = o[n][r];
  __syncthreads();

  // --- merge the 2 KV-halves of each strip; thread -> (strip, row, 16 h) ---
  {
    const int st  = tid >> 7;               // 0: lo strip, 1: hi strip
    const int t7  = tid & 127;
    const int row = t7 >> 3;                // 0..15
    const int hb  = (t7 & 7) * 16;          // 0..112
    const int qbs = st ? (4080 - jj * 16) : (jj * 16);
    const float m0 = ml[2 * st][row][0],  m1 = ml[2 * st + 1][row][0];
    const float M  = fmaxf(m0, m1);
    const float w0 = __expf(m0 - M), w1 = __expf(m1 - M);
    const float lt = w0 * ml[2 * st][row][1] + w1 * ml[2 * st + 1][row][1];
    const float inv = 1.0f / lt;
    float* dst = out + (size_t)(b * 4096 + qbs + row) * 128 + hb;
    #pragma unroll
    for (int j4 = 0; j4 < 4; ++j4) {
      const f4v a = *(const f4v*)(&o_lds[2 * st][row][hb + 4 * j4]);
      const f4v c = *(const f4v*)(&o_lds[2 * st + 1][row][hb + 4 * j4]);
      f4v res;
      #pragma unroll
      for (int j = 0; j < 4; ++j) res[j] = (w0 * a[j] + w1 * c[j]) * inv;
      *(f4v*)(dst + 4 * j4) = res;
    }
  }
}

extern "C" void kernel_launch(void* const* d_in, const int* in_sizes, int n_in,
                              void* d_out, int out_size, void* d_ws, size_t ws_size,
                              hipStream_t stream) {
  const float* x  = (const float*)d_in[0];
  const float* Wq = (const float*)d_in[1];
  const float* Wk = (const float*)d_in[2];
  const float* Wv = (const float*)d_in[3];

  unsigned short* WT = (unsigned short*)d_ws;
  unsigned short* Q  = (unsigned short*)((char*)d_ws + 1572864);
  unsigned short* K  = (unsigned short*)((char*)d_ws + 5767168);
  unsigned short* VT = (unsigned short*)((char*)d_ws + 9961472);
  float* out = (float*)d_out;

  prep_wt<<<3072, 256, 0, stream>>>(Wq, Wk, Wv, WT);
  proj_kernel<<<256, 256, 0, stream>>>(x, WT, Q, K, VT);
  attn_kernel<<<512, 256, 0, stream>>>(Q, K, VT, out);
}

// Round 4
// 159.971 us; speedup vs baseline: 1.5508x; 1.2144x over previous
//
#include <hip/hip_runtime.h>

// ---------------------------------------------------------------------------
// Head: out = softmax(mask((x@Wq)(x@Wk)^T * C^-0.5)) @ (x@Wv)
// B=4 T=4096 C=2048 H=128, fp32 in/out. bf16 MFMA pipeline.
//
// ws layout (bytes):
//   [0)        WT  bf16 [3][128][2048]   (W^T, Wq pre-scaled by C^-0.5)
//   [1572864)  Q   bf16 [16384][128]
//   [5767168)  K   bf16 [16384][128]
//   [9961472)  VT  bf16 [4][128][4096]   (V transposed per batch)
// ---------------------------------------------------------------------------

typedef __attribute__((ext_vector_type(8))) short s8v;   // 8 x bf16 (16B)
typedef __attribute__((ext_vector_type(4))) short s4v;   // 4 x bf16 (8B)
typedef __attribute__((ext_vector_type(4))) float f4v;   // MFMA acc frag

__device__ __forceinline__ unsigned short f2bf(float f) {
  unsigned int b = __float_as_uint(f);
  b += 0x7FFFu + ((b >> 16) & 1u);          // round-to-nearest-even
  return (unsigned short)(b >> 16);
}

#define SCALE_QK 0.02209708691207961f       // 2048^-0.5

// ---- prep: WT[m][h][c] = Wm[c][h] (bf16); m=0 (q) pre-scaled --------------
__global__ void prep_wt(const float* __restrict__ Wq, const float* __restrict__ Wk,
                        const float* __restrict__ Wv, unsigned short* __restrict__ WT) {
  int e = blockIdx.x * 256 + threadIdx.x;   // < 3*262144
  int m = e >> 18;
  int r = e & 262143;                       // r = c*128 + h
  int c = r >> 7, h = r & 127;
  const float* W = (m == 0) ? Wq : (m == 1) ? Wk : Wv;
  float v = W[r];
  if (m == 0) v *= SCALE_QK;
  WT[m * 262144 + h * 2048 + c] = f2bf(v);
}

// ---- projection: block = 64 rows x 384 cols (q|k|v), 8 waves --------------
// wave w covers 64 rows x cols [48w, 48w+48). K-loop BK=32, LDS dbuf,
// pad-40 rows (2-way bank conflicts only). V written transposed via LDS scr.
__global__ __launch_bounds__(512, 2) void proj_kernel(
    const float* __restrict__ x, const unsigned short* __restrict__ WT,
    unsigned short* __restrict__ Qo, unsigned short* __restrict__ Ko,
    unsigned short* __restrict__ VTo)
{
  __shared__ unsigned short Atile[2][64 * 40];    // 64 rows x 32 bf16, pad 40
  __shared__ unsigned short Btile[2][384 * 40];   // 384 cols x 32 bf16, pad 40
  __shared__ unsigned short scr[128 * 72];        // v transpose: [h][64 t], pad 72

  const int tid = threadIdx.x;
  const int wc  = tid >> 6;                 // wave id = column group (0..7)
  const int lane = tid & 63;
  const int l15 = lane & 15;
  const int g   = lane >> 4;
  const int rowbase = blockIdx.x * 64;

  f4v acc[12];
  #pragma unroll
  for (int n = 0; n < 12; ++n) acc[n] = (f4v){0.f, 0.f, 0.f, 0.f};

  // staging: A: thread -> 4 f32 (one f4v); B: thread -> 3 rows x 16B
  const int arow = tid >> 3, ach = tid & 7;
  const float* xsrc = x + (size_t)(rowbase + arow) * 2048 + ach * 4;
  const int brow = tid >> 2, bch = tid & 3;
  const unsigned short* bsrc = WT + (size_t)brow * 2048 + bch * 8;

  f4v xa = *(const f4v*)(xsrc);
  s8v bw[3];
  #pragma unroll
  for (int p = 0; p < 3; ++p) bw[p] = *(const s8v*)(bsrc + (size_t)p * 262144);

  for (int it = 0; it < 64; ++it) {
    const int buf = it & 1;
    s4v aw;
    #pragma unroll
    for (int i = 0; i < 4; ++i) aw[i] = (short)f2bf(xa[i]);
    *(s4v*)(&Atile[buf][arow * 40 + ach * 4]) = aw;
    #pragma unroll
    for (int p = 0; p < 3; ++p)
      *(s8v*)(&Btile[buf][(brow + p * 128) * 40 + bch * 8]) = bw[p];
    __syncthreads();
    if (it < 63) {
      const int k1 = (it + 1) * 32;
      xa = *(const f4v*)(xsrc + k1);
      #pragma unroll
      for (int p = 0; p < 3; ++p)
        bw[p] = *(const s8v*)(bsrc + k1 + (size_t)p * 262144);
    }
    s8v af[4], bfr[3];
    #pragma unroll
    for (int mi = 0; mi < 4; ++mi)
      af[mi] = *(const s8v*)(&Atile[buf][(mi * 16 + l15) * 40 + g * 8]);
    #pragma unroll
    for (int nl = 0; nl < 3; ++nl)
      bfr[nl] = *(const s8v*)(&Btile[buf][(48 * wc + 16 * nl + l15) * 40 + g * 8]);
    #pragma unroll
    for (int mi = 0; mi < 4; ++mi)
      #pragma unroll
      for (int nl = 0; nl < 3; ++nl)
        acc[mi * 3 + nl] = __builtin_amdgcn_mfma_f32_16x16x32_bf16(
            af[mi], bfr[nl], acc[mi * 3 + nl], 0, 0, 0);
  }

  // ---- epilogue: q,k direct; v -> LDS transpose -> VT ----
  #pragma unroll
  for (int mi = 0; mi < 4; ++mi) {
    #pragma unroll
    for (int nl = 0; nl < 3; ++nl) {
      const int colg = 48 * wc + 16 * nl + l15;   // 0..383
      const int m = colg >> 7;                    // 0=q 1=k 2=v
      const int h = colg & 127;
      const f4v a = acc[mi * 3 + nl];
      if (m < 2) {
        unsigned short* dst = (m == 0) ? Qo : Ko;
        #pragma unroll
        for (int r = 0; r < 4; ++r) {
          const int t = rowbase + mi * 16 + 4 * g + r;
          dst[(size_t)t * 128 + h] = f2bf(a[r]);
        }
      } else {
        #pragma unroll
        for (int r = 0; r < 4; ++r) {
          const int tl = mi * 16 + 4 * g + r;     // 0..63
          scr[h * 72 + tl] = f2bf(a[r]);
        }
      }
    }
  }
  __syncthreads();
  {
    const int b   = rowbase >> 12;
    const int tg0 = rowbase & 4095;
    const int h    = tid >> 2;                    // 0..127
    const int toff = (tid & 3) * 16;              // 0..48
    unsigned short* dst = VTo + (size_t)(b * 128 + h) * 4096 + tg0 + toff;
    *(s8v*)(dst)     = *(const s8v*)(&scr[h * 72 + toff]);
    *(s8v*)(dst + 8) = *(const s8v*)(&scr[h * 72 + toff + 8]);
  }
}

// ---- attention ------------------------------------------------------------
// Block = 4 waves, ONE 32-row q-strip. Per 64-col KV tile: K(64x128) and
// VT(128x64) DMA-staged into LDS (global_load_lds w16, XOR-swizzled via
// pre-swizzled global source), double-buffered, shared by all 4 waves.
// Wave w: rows [16*(w>>1), +16), cols [32*(w&1), +32) of each tile; 2-way
// col-merge per 16 rows at the end (LDS, aliasing the KV buffers).
__global__ __launch_bounds__(256, 2) void attn_kernel(
    const unsigned short* __restrict__ Q, const unsigned short* __restrict__ K,
    const unsigned short* __restrict__ VT, float* __restrict__ out)
{
  __shared__ __align__(16) char smem[71168];
  // [0)      KV dbuf: buf c at c*32768: K 16KB, V 16KB    (aliased by merge)
  // [65536)  plds [4][16*40] bf16
  // [70656)  ml   [4][16][2] f32
  unsigned short* plds = (unsigned short*)(smem + 65536);
  float* mlp = (float*)(smem + 70656);

  const int tid  = threadIdx.x;
  const int w    = tid >> 6;
  const int lane = tid & 63;
  const int l15 = lane & 15, g = lane >> 4;

  const int b  = blockIdx.x & 3;                 // batch <-> XCD affinity
  const int s  = 127 - (blockIdx.x >> 2);        // LPT: longest strips first
  const int qb = s * 32;
  const int roff = (w >> 1) * 16, half = w & 1;
  const int ntiles = (qb + 95) >> 6;

  const char* Kg = (const char*)(K  + (size_t)b * 4096 * 128);
  const char* Vg = (const char*)(VT + (size_t)b * 128 * 4096);
  const unsigned short* Qb = Q + (size_t)b * 4096 * 128;

  s8v qf[4];
  #pragma unroll
  for (int kk = 0; kk < 4; ++kk)
    qf[kk] = *(const s8v*)(Qb + (size_t)(qb + roff + l15) * 128 + kk * 32 + g * 8);

  f4v o[8];
  #pragma unroll
  for (int n = 0; n < 8; ++n) o[n] = (f4v){0.f, 0.f, 0.f, 0.f};
  float mrun[4], lrun[4];
  #pragma unroll
  for (int r = 0; r < 4; ++r) { mrun[r] = -1e30f; lrun[r] = 0.f; }

  const int off0 = tid * 16;                     // staging: 16B per thread

  // ---- STAGE macro: DMA tile kvb into buffer at Kl (linear dest,
  //      pre-swizzled global source; XOR stays within one row) ----
#define STAGE(Kl_, kvb_)                                                       \
  {                                                                            \
    char* Kl = (Kl_);                                                          \
    _Pragma("unroll")                                                          \
    for (int p = 0; p < 4; ++p) {                                              \
      const int off = off0 + p * 4096;                                         \
      const int ks = off ^ (((off >> 8) & 7) << 4);                            \
      __builtin_amdgcn_global_load_lds(                                        \
        (const __attribute__((address_space(1))) void*)(Kg + (size_t)(kvb_) * 256 + ks), \
        (__attribute__((address_space(3))) void*)(Kl + off), 16, 0, 0);        \
    }                                                                          \
    _Pragma("unroll")                                                          \
    for (int p = 0; p < 4; ++p) {                                              \
      const int off = off0 + p * 4096;                                         \
      const int h = off >> 7;                                                  \
      const int cs = (off & 127) ^ ((h & 7) << 4);                             \
      __builtin_amdgcn_global_load_lds(                                        \
        (const __attribute__((address_space(1))) void*)(Vg + (size_t)h * 8192 + (size_t)(kvb_) * 2 + cs), \
        (__attribute__((address_space(3))) void*)(Kl + 16384 + off), 16, 0, 0); \
    }                                                                          \
  }

  // prologue: stage tile 0 into buf 0
  STAGE(smem, 0)
  __syncthreads();                               // drains vmcnt

  int cur = 0;
  for (int it = 0; it < ntiles; ++it) {
    const int kvb = it * 64;
    // async-stage next tile into the other buffer (in flight during compute)
    if (it + 1 < ntiles) STAGE(smem + (cur ^ 1) * 32768, kvb + 64)

    const char* Kl = smem + cur * 32768;
    const char* Vl = Kl + 16384;
    // K frags: rows 32*half + 16*t2 + l15 (swizzled read)
    s8v kf[2][4];
    #pragma unroll
    for (int t2 = 0; t2 < 2; ++t2) {
      const int row = half * 32 + t2 * 16 + l15;
      #pragma unroll
      for (int kk = 0; kk < 4; ++kk)
        kf[t2][kk] = *(const s8v*)(Kl + ((row * 256 + kk * 64 + g * 16) ^ ((l15 & 7) << 4)));
    }
    // V frags: VT rows 16n+l15, col-half of this wave
    s8v vf[8];
    #pragma unroll
    for (int n = 0; n < 8; ++n) {
      const int row = n * 16 + l15;
      vf[n] = *(const s8v*)(Vl + ((row * 128 + half * 64 + g * 16) ^ ((l15 & 7) << 4)));
    }
    // QK^T: 8 MFMA
    f4v sc[2];
    sc[0] = (f4v){0.f, 0.f, 0.f, 0.f};
    sc[1] = (f4v){0.f, 0.f, 0.f, 0.f};
    __builtin_amdgcn_s_setprio(1);
    #pragma unroll
    for (int kk = 0; kk < 4; ++kk) {
      sc[0] = __builtin_amdgcn_mfma_f32_16x16x32_bf16(qf[kk], kf[0][kk], sc[0], 0, 0, 0);
      sc[1] = __builtin_amdgcn_mfma_f32_16x16x32_bf16(qf[kk], kf[1][kk], sc[1], 0, 0, 0);
    }
    __builtin_amdgcn_s_setprio(0);
    // causal mask (only the diagonal tile)
    if (it == ntiles - 1) {
      #pragma unroll
      for (int t2 = 0; t2 < 2; ++t2)
        #pragma unroll
        for (int r = 0; r < 4; ++r) {
          const int kv = kvb + half * 32 + t2 * 16 + l15;
          if (kv > qb + roff + 4 * g + r) sc[t2][r] = -1e30f;
        }
    }
    // online softmax (rows live in 16-lane groups)
    float pmax[4];
    #pragma unroll
    for (int r = 0; r < 4; ++r) {
      float v = fmaxf(sc[0][r], sc[1][r]);
      v = fmaxf(v, __shfl_xor(v, 1));
      v = fmaxf(v, __shfl_xor(v, 2));
      v = fmaxf(v, __shfl_xor(v, 4));
      v = fmaxf(v, __shfl_xor(v, 8));
      pmax[r] = v;
    }
    bool grow = false;
    #pragma unroll
    for (int r = 0; r < 4; ++r) grow |= (pmax[r] > mrun[r] + 4.0f);
    if (__any(grow)) {                           // defer-max (T13)
      #pragma unroll
      for (int r = 0; r < 4; ++r) {
        const float mnew = fmaxf(mrun[r], pmax[r]);
        const float corr = __expf(mrun[r] - mnew);
        mrun[r] = mnew;
        lrun[r] *= corr;
        #pragma unroll
        for (int n = 0; n < 8; ++n) o[n][r] *= corr;
      }
    }
    f4v p0, p1;
    #pragma unroll
    for (int r = 0; r < 4; ++r) {
      p0[r] = __expf(sc[0][r] - mrun[r]);
      p1[r] = __expf(sc[1][r] - mrun[r]);
      lrun[r] += p0[r] + p1[r];
    }
    // P: D-layout -> LDS -> A-frag (per-wave pad-40 buffer)
    unsigned short* pw = plds + w * 640;
    #pragma unroll
    for (int r = 0; r < 4; ++r) {
      pw[(4 * g + r) * 40 + l15]      = f2bf(p0[r]);
      pw[(4 * g + r) * 40 + 16 + l15] = f2bf(p1[r]);
    }
    const s8v pfv = *(const s8v*)(pw + l15 * 40 + g * 8);
    // PV: 8 MFMA
    __builtin_amdgcn_s_setprio(1);
    #pragma unroll
    for (int n = 0; n < 8; ++n)
      o[n] = __builtin_amdgcn_mfma_f32_16x16x32_bf16(pfv, vf[n], o[n], 0, 0, 0);
    __builtin_amdgcn_s_setprio(0);

    __syncthreads();                             // drains staging DMA + syncs
    cur ^= 1;
  }
#undef STAGE

  // ---- per-wave finish: l reduce, dump {m,l,o} partials ----
  #pragma unroll
  for (int r = 0; r < 4; ++r) {
    float sl = lrun[r];
    sl += __shfl_xor(sl, 1);
    sl += __shfl_xor(sl, 2);
    sl += __shfl_xor(sl, 4);
    sl += __shfl_xor(sl, 8);
    if (l15 == 0) {
      mlp[(w * 16 + 4 * g + r) * 2 + 0] = mrun[r];
      mlp[(w * 16 + 4 * g + r) * 2 + 1] = sl;
    }
  }
  float* ol = (float*)smem;                      // [4][16][132] aliases KV bufs
  #pragma unroll
  for (int n = 0; n < 8; ++n)
    #pragma unroll
    for (int r = 0; r < 4; ++r)
      ol[(w * 16 + 4 * g + r) * 132 + 16 * n + l15] = o[n][r];
  __syncthreads();

  // ---- merge the 2 col-halves of each 16-row group ----
  {
    const int st  = tid >> 7;                    // row group 0/1
    const int t7  = tid & 127;
    const int row = t7 >> 3;                     // 0..15
    const int hb  = (t7 & 7) * 16;               // 0..112
    const int wA = 2 * st, wB = 2 * st + 1;
    const float m0 = mlp[(wA * 16 + row) * 2], l0 = mlp[(wA * 16 + row) * 2 + 1];
    const float m1 = mlp[(wB * 16 + row) * 2], l1 = mlp[(wB * 16 + row) * 2 + 1];
    const float M  = fmaxf(m0, m1);
    const float w0 = __expf(m0 - M), w1 = __expf(m1 - M);
    const float inv = 1.0f / (w0 * l0 + w1 * l1);
    float* dst = out + (size_t)(b * 4096 + qb + 16 * st + row) * 128 + hb;
    #pragma unroll
    for (int j4 = 0; j4 < 4; ++j4) {
      const f4v a = *(const f4v*)(&ol[(wA * 16 + row) * 132 + hb + 4 * j4]);
      const f4v c = *(const f4v*)(&ol[(wB * 16 + row) * 132 + hb + 4 * j4]);
      f4v res;
      #pragma unroll
      for (int j = 0; j < 4; ++j) res[j] = (w0 * a[j] + w1 * c[j]) * inv;
      *(f4v*)(dst + 4 * j4) = res;
    }
  }
}

extern "C" void kernel_launch(void* const* d_in, const int* in_sizes, int n_in,
                              void* d_out, int out_size, void* d_ws, size_t ws_size,
                              hipStream_t stream) {
  const float* x  = (const float*)d_in[0];
  const float* Wq = (const float*)d_in[1];
  const float* Wk = (const float*)d_in[2];
  const float* Wv = (const float*)d_in[3];

  unsigned short* WT = (unsigned short*)d_ws;
  unsigned short* Q  = (unsigned short*)((char*)d_ws + 1572864);
  unsigned short* K  = (unsigned short*)((char*)d_ws + 5767168);
  unsigned short* VT = (unsigned short*)((char*)d_ws + 9961472);
  float* out = (float*)d_out;

  prep_wt<<<3072, 256, 0, stream>>>(Wq, Wk, Wv, WT);
  proj_kernel<<<256, 512, 0, stream>>>(x, WT, Q, K, VT);
  attn_kernel<<<512, 256, 0, stream>>>(Q, K, VT, out);
}